// Round 4
// baseline (593.755 us; speedup 1.0000x reference)
//
#include <hip/hip_runtime.h>
#include <hip/hip_bf16.h>
#include <cstdint>
#include <cstddef>

typedef __attribute__((ext_vector_type(8))) short  s8v;
typedef __attribute__((ext_vector_type(4))) short  s4v;
typedef __attribute__((ext_vector_type(8))) __bf16 b8v;
typedef __attribute__((ext_vector_type(4))) float  f32x4;
typedef __attribute__((ext_vector_type(4))) unsigned u32x4;

__device__ __forceinline__ short f2bf(float f){
  unsigned u = __builtin_bit_cast(unsigned, f);
  unsigned r = (u + 0x7fffu + ((u >> 16) & 1u)) >> 16;   // RNE
  return (short)(unsigned short)r;
}

__device__ __forceinline__ f32x4 mfma16(s8v a, s8v b, f32x4 c){
  return __builtin_amdgcn_mfma_f32_16x16x32_bf16(
      __builtin_bit_cast(b8v, a), __builtin_bit_cast(b8v, b), c, 0, 0, 0);
}

__device__ __forceinline__ unsigned cvtpk(float a, float b){
  unsigned w;
  asm("v_cvt_pk_bf16_f32 %0, %1, %2" : "=v"(w) : "v"(a), "v"(b));
  return w;
}

// ---------------- LayerNorm over E=1024 -> bf16 ----------------
__global__ __launch_bounds__(256)
void ln_k(const float* __restrict__ x, const float* __restrict__ g,
          const float* __restrict__ b, short* __restrict__ out)
{
  const int row = blockIdx.x, tid = threadIdx.x;
  const float4 v = ((const float4*)(x + (size_t)row*1024))[tid];
  float s  = v.x+v.y+v.z+v.w;
  float s2 = v.x*v.x+v.y*v.y+v.z*v.z+v.w*v.w;
  #pragma unroll
  for (int off=32; off; off>>=1){ s += __shfl_down(s, off); s2 += __shfl_down(s2, off); }
  __shared__ float red[8];
  const int wave = tid>>6, lane = tid&63;
  if (lane==0){ red[wave]=s; red[4+wave]=s2; }
  __syncthreads();
  s  = red[0]+red[1]+red[2]+red[3];
  s2 = red[4]+red[5]+red[6]+red[7];
  const float mean = s*(1.f/1024.f);
  const float rstd = rsqrtf(s2*(1.f/1024.f) - mean*mean + 1e-5f);
  const float4 gv = ((const float4*)g)[tid];
  const float4 bv = ((const float4*)b)[tid];
  s4v o;
  o[0] = f2bf((v.x-mean)*rstd*gv.x + bv.x);
  o[1] = f2bf((v.y-mean)*rstd*gv.y + bv.y);
  o[2] = f2bf((v.z-mean)*rstd*gv.z + bv.z);
  o[3] = f2bf((v.w-mean)*rstd*gv.w + bv.w);
  *(s4v*)(out + (size_t)row*1024 + tid*4) = o;
}

// ---------------- f32 -> bf16 cast (4 elems/thread) ----------------
__global__ __launch_bounds__(256)
void cast_k(const float* __restrict__ in, short* __restrict__ out)
{
  const int i = blockIdx.x*256 + threadIdx.x;
  const float4 v = ((const float4*)in)[i];
  s4v o; o[0]=f2bf(v.x); o[1]=f2bf(v.y); o[2]=f2bf(v.z); o[3]=f2bf(v.w);
  ((s4v*)out)[i] = o;
}

// ------- transpose+cast: in (gridDim.z, E2, D2) f32 -> out (gridDim.z*D2, E2) bf16 -------
__global__ __launch_bounds__(256)
void tcast_k(const float* __restrict__ in, short* __restrict__ out, int E2, int D2)
{
  __shared__ float t[32][33];
  const int h  = blockIdx.z;
  const int e0 = blockIdx.x*32, d0 = blockIdx.y*32;
  const int tx = threadIdx.x & 31, ty = threadIdx.x >> 5;
  const float* ip = in + (size_t)h*E2*D2;
  #pragma unroll
  for (int r = ty; r < 32; r += 8)
    t[r][tx] = ip[(size_t)(e0+r)*D2 + d0 + tx];
  __syncthreads();
  short* op = out + (size_t)h*D2*E2;
  #pragma unroll
  for (int r = ty; r < 32; r += 8)
    op[(size_t)(d0+r)*E2 + e0 + tx] = f2bf(t[tx][r]);
}

// ------- bf16 transpose: V (b, s, h, d) strided -> Vt[b][h][d][s] -------
__global__ __launch_bounds__(256)
void vtrans_k(const short* __restrict__ V, int ldv, short* __restrict__ Vt, int S, int H)
{
  __shared__ short t[32][34];
  const int bh = blockIdx.z;
  const int b = bh / H, h = bh % H;
  const int s0 = blockIdx.x*32, d0 = blockIdx.y*32;
  const int tx = threadIdx.x & 31, ty = threadIdx.x >> 5;
  const short* ip = V + (size_t)b*S*ldv + h*64;
  #pragma unroll
  for (int r = ty; r < 32; r += 8)
    t[r][tx] = ip[(size_t)(s0+r)*ldv + d0 + tx];
  __syncthreads();
  short* op = Vt + ((size_t)bh*64 + d0)*S + s0;
  #pragma unroll
  for (int r = ty; r < 32; r += 8)
    op[(size_t)r*S + tx] = t[tx][r];
}

// ---------------- bf16 MFMA GEMM: C = A(M,K) * Bt(N,K)^T  (m97 structure) ----------------
template<int BIAS, int RELU, int RESID, int WF32>
__global__ __launch_bounds__(256, 2)
void gemm_bt(const short* __restrict__ A, const short* __restrict__ Bt,
             const float* __restrict__ bias, const float* __restrict__ resid,
             short* __restrict__ Cb, float* __restrict__ Cf,
             int M, int N, int K)
{
  __shared__ short lds[2][2][128*32];
  const int m0 = blockIdx.y*128, n0 = blockIdx.x*128;
  const int tid  = threadIdx.x;
  const int wave = tid>>6, lane = tid&63;
  const int lo = lane&15, hi = lane>>4;
  const int wm = wave>>1, wn = wave&1;

  f32x4 acc[4][4] = {};
  const int NK = K >> 5;

  auto stage = [&](int buf, int kt){
    const short* Ag = A  + (size_t)m0*K + kt*32;
    const short* Bg = Bt + (size_t)n0*K + kt*32;
    #pragma unroll
    for (int c=0;c<2;c++){
      const int q = (wave*2+c)*64 + lane;
      const int r = q>>2, cc = q&3;
      __builtin_amdgcn_global_load_lds(
        (const __attribute__((address_space(1))) void*)(Ag + (size_t)r*K + cc*8),
        (__attribute__((address_space(3))) void*)(&lds[buf][0][(wave*2+c)*512]),
        16, 0, 0);
      __builtin_amdgcn_global_load_lds(
        (const __attribute__((address_space(1))) void*)(Bg + (size_t)r*K + cc*8),
        (__attribute__((address_space(3))) void*)(&lds[buf][1][(wave*2+c)*512]),
        16, 0, 0);
    }
  };

  stage(0, 0);
  int cur = 0;
  for (int kt=0; kt<NK; kt++){
    __syncthreads();
    if (kt+1 < NK) stage(cur^1, kt+1);
    const short* la = &lds[cur][0][0];
    const short* lb = &lds[cur][1][0];
    s8v af[4], bfr[4];
    #pragma unroll
    for (int i=0;i<4;i++)
      af[i] = *(const s8v*)(la + (wm*64 + i*16 + lo)*32 + hi*8);
    #pragma unroll
    for (int j=0;j<4;j++)
      bfr[j] = *(const s8v*)(lb + (wn*64 + j*16 + lo)*32 + hi*8);
    #pragma unroll
    for (int i=0;i<4;i++)
      #pragma unroll
      for (int j=0;j<4;j++)
        acc[i][j] = mfma16(af[i], bfr[j], acc[i][j]);
    cur ^= 1;
  }

  #pragma unroll
  for (int i=0;i<4;i++){
    const int row = m0 + wm*64 + i*16 + hi*4;
    #pragma unroll
    for (int j=0;j<4;j++){
      const int col = n0 + wn*64 + j*16 + lo;
      const float bv = BIAS ? bias[col] : 0.0f;
      #pragma unroll
      for (int r=0;r<4;r++){
        float v = acc[i][j][r] + bv;
        if (RELU) v = fmaxf(v, 0.0f);
        const size_t idx = (size_t)(row + r)*N + col;
        if (RESID) v += resid[idx];
        if (WF32) Cf[idx] = v; else Cb[idx] = f2bf(v);
      }
    }
  }
}

// -------- flash attention, swapped QK^T -> in-register softmax (no LDS) --------
// grid (B*H, T/64); 4 waves x 16 Q rows; each lane owns one q-row (t = t0 + lane&15).
template<int CAUSAL>
__global__ __launch_bounds__(256)
void attn_k(const short* __restrict__ Q, int ldq,
            const short* __restrict__ K, int ldk,
            const short* __restrict__ Vt, int ldvt,   // Vt[b*H+h][d][s]
            const int* __restrict__ msk,
            short* __restrict__ O, int ldo,
            int H, int Tq, int Sk)
{
  const int bh = blockIdx.x;
  const int b = bh / H, h = bh % H;
  const int tid = threadIdx.x;
  const int wave = tid>>6, lane = tid&63;
  const int lo = lane&15, hi = lane>>4;
  const int t0 = blockIdx.y*64 + wave*16;

  const short* Qb  = Q + (size_t)(b*Tq)*ldq + h*64;
  const short* Kb  = K + (size_t)(b*Sk)*ldk + h*64;
  const short* Vtb = Vt + (size_t)bh*64*ldvt;
  const int*   mb  = msk + (size_t)b*Sk;

  // Q as MFMA B-operand: row j = lo -> q-row t0+lo, k = 8*hi+e
  const short* qp = Qb + (size_t)(t0+lo)*ldq + hi*8;
  const s8v qa0 = *(const s8v*)(qp);
  const s8v qa1 = *(const s8v*)(qp + 32);

  float mrow = -INFINITY, lrow = 0.f;
  f32x4 oacc[4] = {};
  const int trow = t0 + lo;
  const int nblk = CAUSAL ? ((t0>>6) + 1) : (Sk>>6);
  const float sc2 = 0.03125f * 1.44269504088896f;   // E^-0.5 * log2(e)

  for (int it=0; it<nblk; it++){
    const int s0 = it*64;
    // ---- K as MFMA A-operand: row i = lo -> s = s0+16g+lo ----
    s8v kf[4][2];
    #pragma unroll
    for (int g=0; g<4; g++){
      const short* kp = Kb + (size_t)(s0+g*16+lo)*ldk + hi*8;
      kf[g][0] = *(const s8v*)(kp);
      kf[g][1] = *(const s8v*)(kp + 32);
    }
    // ---- mask (int4 over s = s0+16g+4hi+{0..3}) ----
    int ka[4][4];
    #pragma unroll
    for (int g=0; g<4; g++){
      const int4 kv = ((const int4*)mb)[(s0>>2) + g*4 + hi];
      ka[g][0]=kv.x; ka[g][1]=kv.y; ka[g][2]=kv.z; ka[g][3]=kv.w;
    }
    // ---- V fragments, custom k-map: slot(hi,e) <-> s = s0+ks*32+16*(e>>2)+4hi+(e&3) ----
    s4v vf[4][4];
    #pragma unroll
    for (int f=0; f<4; f++){
      const short* vp = Vtb + (size_t)(f*16+lo)*ldvt + s0 + 4*hi;
      vf[f][0] = *(const s4v*)(vp);
      vf[f][1] = *(const s4v*)(vp + 16);
      vf[f][2] = *(const s4v*)(vp + 32);
      vf[f][3] = *(const s4v*)(vp + 48);
    }

    // ---- QK^T swapped: S^T, lane holds S[t=lo][s=s0+16g+4hi+r] ----
    f32x4 sg[4] = {};
    __builtin_amdgcn_s_setprio(1);
    #pragma unroll
    for (int g=0; g<4; g++){
      sg[g] = mfma16(kf[g][0], qa0, sg[g]);
      sg[g] = mfma16(kf[g][1], qa1, sg[g]);
    }
    __builtin_amdgcn_s_setprio(0);

    // ---- scale + mask ----
    const bool lastblk = CAUSAL && (it == nblk-1);
    float p[4][4];
    #pragma unroll
    for (int g=0; g<4; g++)
      #pragma unroll
      for (int r=0; r<4; r++){
        const int sidx = s0 + g*16 + 4*hi + r;
        const bool ok = ka[g][r] && (!lastblk || sidx <= trow);
        p[g][r] = ok ? sg[g][r]*sc2 : -1.5e9f;
      }

    // ---- row max: in-lane tree + 2 cross-lane rounds ----
    float bmax;
    {
      float m0_ = fmaxf(fmaxf(p[0][0],p[0][1]), fmaxf(p[0][2],p[0][3]));
      float m1_ = fmaxf(fmaxf(p[1][0],p[1][1]), fmaxf(p[1][2],p[1][3]));
      float m2_ = fmaxf(fmaxf(p[2][0],p[2][1]), fmaxf(p[2][2],p[2][3]));
      float m3_ = fmaxf(fmaxf(p[3][0],p[3][1]), fmaxf(p[3][2],p[3][3]));
      bmax = fmaxf(fmaxf(m0_,m1_), fmaxf(m2_,m3_));
    }
    bmax = fmaxf(bmax, __shfl_xor(bmax, 16));
    bmax = fmaxf(bmax, __shfl_xor(bmax, 32));

    const float mn  = fmaxf(mrow, bmax);
    const float fac = exp2f(mrow - mn);        // first iter: exp2(-inf)=0
    mrow = mn;
    #pragma unroll
    for (int g=0; g<4; g++)
      #pragma unroll
      for (int r=0; r<4; r++)
        p[g][r] = exp2f(p[g][r] - mn);

    float bsum;
    {
      float s0_ = (p[0][0]+p[0][1]) + (p[0][2]+p[0][3]);
      float s1_ = (p[1][0]+p[1][1]) + (p[1][2]+p[1][3]);
      float s2_ = (p[2][0]+p[2][1]) + (p[2][2]+p[2][3]);
      float s3_ = (p[3][0]+p[3][1]) + (p[3][2]+p[3][3]);
      bsum = (s0_+s1_) + (s2_+s3_);
    }
    bsum += __shfl_xor(bsum, 16);
    bsum += __shfl_xor(bsum, 32);
    lrow = lrow*fac + bsum;
    #pragma unroll
    for (int f=0; f<4; f++)
      #pragma unroll
      for (int r=0; r<4; r++)
        oacc[f][r] *= fac;

    // ---- pack P -> bf16 B-operand (same custom k-map as V; no cross-lane!) ----
    u32x4 pw0, pw1;
    pw0[0] = cvtpk(p[0][0], p[0][1]);
    pw0[1] = cvtpk(p[0][2], p[0][3]);
    pw0[2] = cvtpk(p[1][0], p[1][1]);
    pw0[3] = cvtpk(p[1][2], p[1][3]);
    pw1[0] = cvtpk(p[2][0], p[2][1]);
    pw1[1] = cvtpk(p[2][2], p[2][3]);
    pw1[2] = cvtpk(p[3][0], p[3][1]);
    pw1[3] = cvtpk(p[3][2], p[3][3]);
    const s8v pb0 = __builtin_bit_cast(s8v, pw0);
    const s8v pb1 = __builtin_bit_cast(s8v, pw1);

    // ---- PV: O^T accumulate, lane col = t, rows = d = f*16+4hi+r ----
    __builtin_amdgcn_s_setprio(1);
    #pragma unroll
    for (int f=0; f<4; f++){
      const s8v av0 = __builtin_shufflevector(vf[f][0], vf[f][1], 0,1,2,3,4,5,6,7);
      const s8v av1 = __builtin_shufflevector(vf[f][2], vf[f][3], 0,1,2,3,4,5,6,7);
      oacc[f] = mfma16(av0, pb0, oacc[f]);
      oacc[f] = mfma16(av1, pb1, oacc[f]);
    }
    __builtin_amdgcn_s_setprio(0);
  }

  // ---- write O[t = t0+lo][d = f*16+4hi+r] : 8B stores ----
  const float inv = 1.0f / lrow;
  short* Ob = O + (size_t)(b*Tq)*ldo + h*64 + (size_t)(t0+lo)*ldo + 4*hi;
  #pragma unroll
  for (int f=0; f<4; f++){
    s4v o;
    #pragma unroll
    for (int r=0; r<4; r++) o[r] = f2bf(oacc[f][r]*inv);
    *(s4v*)(Ob + f*16) = o;
  }
}

// =============================== host ===============================
extern "C" void kernel_launch(void* const* d_in, const int* in_sizes, int n_in,
                              void* d_out, int out_size, void* d_ws, size_t ws_size,
                              hipStream_t stream)
{
  (void)in_sizes; (void)n_in; (void)out_size; (void)ws_size;
  const float* x    = (const float*)d_in[0];
  const int*   xm   = (const int*)  d_in[1];
  const float* ca   = (const float*)d_in[2];
  const int*   cam  = (const int*)  d_in[3];
  const float* Wq_s = (const float*)d_in[4];
  const float* Wk_s = (const float*)d_in[5];
  const float* Wv_s = (const float*)d_in[6];
  const float* Wo_s = (const float*)d_in[7];
  const float* bo_s = (const float*)d_in[8];
  const float* Wq_c = (const float*)d_in[9];
  const float* Wk_c = (const float*)d_in[10];
  const float* Wv_c = (const float*)d_in[11];
  const float* Wo_c = (const float*)d_in[12];
  const float* bo_c = (const float*)d_in[13];
  const float* ln1g = (const float*)d_in[14];
  const float* ln1b = (const float*)d_in[15];
  const float* ln2g = (const float*)d_in[16];
  const float* ln2b = (const float*)d_in[17];
  const float* ln3g = (const float*)d_in[18];
  const float* ln3b = (const float*)d_in[19];
  const float* W1   = (const float*)d_in[20];
  const float* b1   = (const float*)d_in[21];
  const float* W2   = (const float*)d_in[22];
  const float* b2   = (const float*)d_in[23];
  float* out = (float*)d_out;

  char* ws = (char*)d_ws;
  size_t off = 0;
  auto alloc = [&](size_t bytes)->void*{
    void* p = ws + off; off += (bytes + 255) & ~(size_t)255; return p; };

  short* w_qkv_s = (short*)alloc((size_t)3072*1024*2);
  short* w_o_s   = (short*)alloc((size_t)1024*1024*2);
  short* w_q_c   = (short*)alloc((size_t)1024*1024*2);
  short* w_kv_c  = (short*)alloc((size_t)2048*1024*2);
  short* w_o_c   = (short*)alloc((size_t)1024*1024*2);
  short* w_1     = (short*)alloc((size_t)4096*1024*2);
  short* w_2     = (short*)alloc((size_t)1024*4096*2);
  short* xn      = (short*)alloc((size_t)4096*1024*2);
  short* cab     = (short*)alloc((size_t)4096*1024*2);
  short* qkv     = (short*)alloc((size_t)4096*3072*2);
  short* attno   = (short*)alloc((size_t)4096*1024*2);
  float* xres    = (float*)alloc((size_t)4096*1024*4);
  short* hffn    = (short*)alloc((size_t)4096*4096*2);
  short* kvbuf   = qkv + (size_t)4096*1024;
  // Vt buffers alias hffn (disjoint live ranges: attn phases vs FFN phase)
  short* vt_s    = hffn;                           // 64 heads * 64 * 1024
  short* vt_c    = hffn + (size_t)4*1024*1024;

  // weight repacks -> B^T (N,K) bf16
  tcast_k<<<dim3(32,  2,16),256,0,stream>>>(Wq_s, w_qkv_s,           1024,   64);
  tcast_k<<<dim3(32,  2,16),256,0,stream>>>(Wk_s, w_qkv_s+1024*1024, 1024,   64);
  tcast_k<<<dim3(32,  2,16),256,0,stream>>>(Wv_s, w_qkv_s+2048*1024, 1024,   64);
  tcast_k<<<dim3(32, 32, 1),256,0,stream>>>(Wo_s, w_o_s,             1024, 1024);
  tcast_k<<<dim3(32,  2,16),256,0,stream>>>(Wq_c, w_q_c,             1024,   64);
  tcast_k<<<dim3(32,  2,16),256,0,stream>>>(Wk_c, w_kv_c,            1024,   64);
  tcast_k<<<dim3(32,  2,16),256,0,stream>>>(Wv_c, w_kv_c+1024*1024,  1024,   64);
  tcast_k<<<dim3(32, 32, 1),256,0,stream>>>(Wo_c, w_o_c,             1024, 1024);
  tcast_k<<<dim3(32,128, 1),256,0,stream>>>(W1,   w_1,               1024, 4096);
  tcast_k<<<dim3(128,32, 1),256,0,stream>>>(W2,   w_2,               4096, 1024);
  cast_k<<<4096,256,0,stream>>>(ca, cab);

  // --- self attention ---
  ln_k<<<4096,256,0,stream>>>(x, ln1g, ln1b, xn);
  gemm_bt<0,0,0,0><<<dim3(24,32),256,0,stream>>>(xn, w_qkv_s, nullptr, nullptr,
                                                 qkv, nullptr, 4096, 3072, 1024);
  vtrans_k<<<dim3(32,2,64),256,0,stream>>>(qkv+2048, 3072, vt_s, 1024, 16);
  attn_k<1><<<dim3(64,16),256,0,stream>>>(qkv, 3072, qkv+1024, 3072, vt_s, 1024,
                                          xm, attno, 1024, 16, 1024, 1024);
  gemm_bt<1,0,1,1><<<dim3(8,32),256,0,stream>>>(attno, w_o_s, bo_s, x,
                                                nullptr, xres, 4096, 1024, 1024);

  // --- cross attention (K,V from raw ca) ---
  ln_k<<<4096,256,0,stream>>>(xres, ln2g, ln2b, xn);
  gemm_bt<0,0,0,0><<<dim3(8,32),256,0,stream>>>(xn, w_q_c, nullptr, nullptr,
                                                qkv, nullptr, 4096, 1024, 1024);
  gemm_bt<0,0,0,0><<<dim3(16,32),256,0,stream>>>(cab, w_kv_c, nullptr, nullptr,
                                                 kvbuf, nullptr, 4096, 2048, 1024);
  vtrans_k<<<dim3(32,2,64),256,0,stream>>>(kvbuf+1024, 2048, vt_c, 1024, 16);
  attn_k<0><<<dim3(64,16),256,0,stream>>>(qkv, 1024, kvbuf, 2048, vt_c, 1024,
                                          cam, attno, 1024, 16, 1024, 1024);
  gemm_bt<1,0,1,1><<<dim3(8,32),256,0,stream>>>(attno, w_o_c, bo_c, xres,
                                                nullptr, xres, 4096, 1024, 1024);

  // --- FFN ---
  ln_k<<<4096,256,0,stream>>>(xres, ln3g, ln3b, xn);
  gemm_bt<1,1,0,0><<<dim3(32,32),256,0,stream>>>(xn, w_1, b1, nullptr,
                                                 hffn, nullptr, 4096, 4096, 1024);
  gemm_bt<1,0,1,1><<<dim3(8,32),256,0,stream>>>(hffn, w_2, b2, xres,
                                                nullptr, out, 4096, 1024, 4096);
}

// Round 5
// 392.325 us; speedup vs baseline: 1.5134x; 1.5134x over previous
//
#include <hip/hip_runtime.h>
#include <hip/hip_bf16.h>
#include <cstdint>
#include <cstddef>

typedef __attribute__((ext_vector_type(8))) short  s8v;
typedef __attribute__((ext_vector_type(4))) short  s4v;
typedef __attribute__((ext_vector_type(8))) __bf16 b8v;
typedef __attribute__((ext_vector_type(4))) float  f32x4;
typedef __attribute__((ext_vector_type(4))) unsigned u32x4;

__device__ __forceinline__ short f2bf(float f){
  unsigned u = __builtin_bit_cast(unsigned, f);
  unsigned r = (u + 0x7fffu + ((u >> 16) & 1u)) >> 16;   // RNE
  return (short)(unsigned short)r;
}

__device__ __forceinline__ f32x4 mfma16(s8v a, s8v b, f32x4 c){
  return __builtin_amdgcn_mfma_f32_16x16x32_bf16(
      __builtin_bit_cast(b8v, a), __builtin_bit_cast(b8v, b), c, 0, 0, 0);
}

__device__ __forceinline__ unsigned cvtpk(float a, float b){
  unsigned w;
  asm("v_cvt_pk_bf16_f32 %0, %1, %2" : "=v"(w) : "v"(a), "v"(b));
  return w;
}

// ---------------- LayerNorm over E=1024 -> bf16 ----------------
__global__ __launch_bounds__(256)
void ln_k(const float* __restrict__ x, const float* __restrict__ g,
          const float* __restrict__ b, short* __restrict__ out)
{
  const int row = blockIdx.x, tid = threadIdx.x;
  const float4 v = ((const float4*)(x + (size_t)row*1024))[tid];
  float s  = v.x+v.y+v.z+v.w;
  float s2 = v.x*v.x+v.y*v.y+v.z*v.z+v.w*v.w;
  #pragma unroll
  for (int off=32; off; off>>=1){ s += __shfl_down(s, off); s2 += __shfl_down(s2, off); }
  __shared__ float red[8];
  const int wave = tid>>6, lane = tid&63;
  if (lane==0){ red[wave]=s; red[4+wave]=s2; }
  __syncthreads();
  s  = red[0]+red[1]+red[2]+red[3];
  s2 = red[4]+red[5]+red[6]+red[7];
  const float mean = s*(1.f/1024.f);
  const float rstd = rsqrtf(s2*(1.f/1024.f) - mean*mean + 1e-5f);
  const float4 gv = ((const float4*)g)[tid];
  const float4 bv = ((const float4*)b)[tid];
  s4v o;
  o[0] = f2bf((v.x-mean)*rstd*gv.x + bv.x);
  o[1] = f2bf((v.y-mean)*rstd*gv.y + bv.y);
  o[2] = f2bf((v.z-mean)*rstd*gv.z + bv.z);
  o[3] = f2bf((v.w-mean)*rstd*gv.w + bv.w);
  *(s4v*)(out + (size_t)row*1024 + tid*4) = o;
}

// ---------------- f32 -> bf16 cast (4 elems/thread) ----------------
__global__ __launch_bounds__(256)
void cast_k(const float* __restrict__ in, short* __restrict__ out)
{
  const int i = blockIdx.x*256 + threadIdx.x;
  const float4 v = ((const float4*)in)[i];
  s4v o; o[0]=f2bf(v.x); o[1]=f2bf(v.y); o[2]=f2bf(v.z); o[3]=f2bf(v.w);
  ((s4v*)out)[i] = o;
}

// ------- transpose+cast: in (gridDim.z, E2, D2) f32 -> out (gridDim.z*D2, E2) bf16 -------
__global__ __launch_bounds__(256)
void tcast_k(const float* __restrict__ in, short* __restrict__ out, int E2, int D2)
{
  __shared__ float t[32][33];
  const int h  = blockIdx.z;
  const int e0 = blockIdx.x*32, d0 = blockIdx.y*32;
  const int tx = threadIdx.x & 31, ty = threadIdx.x >> 5;
  const float* ip = in + (size_t)h*E2*D2;
  #pragma unroll
  for (int r = ty; r < 32; r += 8)
    t[r][tx] = ip[(size_t)(e0+r)*D2 + d0 + tx];
  __syncthreads();
  short* op = out + (size_t)h*D2*E2;
  #pragma unroll
  for (int r = ty; r < 32; r += 8)
    op[(size_t)(d0+r)*E2 + e0 + tx] = f2bf(t[tx][r]);
}

// ------- bf16 transpose: V (b, s, h, d) strided -> Vt[b][h][d][s] -------
__global__ __launch_bounds__(256)
void vtrans_k(const short* __restrict__ V, int ldv, short* __restrict__ Vt, int S, int H)
{
  __shared__ short t[32][34];
  const int bh = blockIdx.z;
  const int b = bh / H, h = bh % H;
  const int s0 = blockIdx.x*32, d0 = blockIdx.y*32;
  const int tx = threadIdx.x & 31, ty = threadIdx.x >> 5;
  const short* ip = V + (size_t)b*S*ldv + h*64;
  #pragma unroll
  for (int r = ty; r < 32; r += 8)
    t[r][tx] = ip[(size_t)(s0+r)*ldv + d0 + tx];
  __syncthreads();
  short* op = Vt + ((size_t)bh*64 + d0)*S + s0;
  #pragma unroll
  for (int r = ty; r < 32; r += 8)
    op[(size_t)r*S + tx] = t[tx][r];
}

// ---------------- bf16 MFMA GEMM: C = A(M,K) * Bt(N,K)^T  (m97 structure) ----------------
template<int BIAS, int RELU, int RESID, int WF32>
__global__ __launch_bounds__(256, 2)
void gemm_bt(const short* __restrict__ A, const short* __restrict__ Bt,
             const float* __restrict__ bias, const float* __restrict__ resid,
             short* __restrict__ Cb, float* __restrict__ Cf,
             int M, int N, int K)
{
  __shared__ short lds[2][2][128*32];
  const int m0 = blockIdx.y*128, n0 = blockIdx.x*128;
  const int tid  = threadIdx.x;
  const int wave = tid>>6, lane = tid&63;
  const int lo = lane&15, hi = lane>>4;
  const int wm = wave>>1, wn = wave&1;

  f32x4 acc[4][4] = {};
  const int NK = K >> 5;

  auto stage = [&](int buf, int kt){
    const short* Ag = A  + (size_t)m0*K + kt*32;
    const short* Bg = Bt + (size_t)n0*K + kt*32;
    #pragma unroll
    for (int c=0;c<2;c++){
      const int q = (wave*2+c)*64 + lane;
      const int r = q>>2, cc = q&3;
      __builtin_amdgcn_global_load_lds(
        (const __attribute__((address_space(1))) void*)(Ag + (size_t)r*K + cc*8),
        (__attribute__((address_space(3))) void*)(&lds[buf][0][(wave*2+c)*512]),
        16, 0, 0);
      __builtin_amdgcn_global_load_lds(
        (const __attribute__((address_space(1))) void*)(Bg + (size_t)r*K + cc*8),
        (__attribute__((address_space(3))) void*)(&lds[buf][1][(wave*2+c)*512]),
        16, 0, 0);
    }
  };

  stage(0, 0);
  int cur = 0;
  for (int kt=0; kt<NK; kt++){
    __syncthreads();
    if (kt+1 < NK) stage(cur^1, kt+1);
    const short* la = &lds[cur][0][0];
    const short* lb = &lds[cur][1][0];
    s8v af[4], bfr[4];
    #pragma unroll
    for (int i=0;i<4;i++)
      af[i] = *(const s8v*)(la + (wm*64 + i*16 + lo)*32 + hi*8);
    #pragma unroll
    for (int j=0;j<4;j++)
      bfr[j] = *(const s8v*)(lb + (wn*64 + j*16 + lo)*32 + hi*8);
    #pragma unroll
    for (int i=0;i<4;i++)
      #pragma unroll
      for (int j=0;j<4;j++)
        acc[i][j] = mfma16(af[i], bfr[j], acc[i][j]);
    cur ^= 1;
  }

  #pragma unroll
  for (int i=0;i<4;i++){
    const int row = m0 + wm*64 + i*16 + hi*4;
    #pragma unroll
    for (int j=0;j<4;j++){
      const int col = n0 + wn*64 + j*16 + lo;
      const float bv = BIAS ? bias[col] : 0.0f;
      #pragma unroll
      for (int r=0;r<4;r++){
        float v = acc[i][j][r] + bv;
        if (RELU) v = fmaxf(v, 0.0f);
        const size_t idx = (size_t)(row + r)*N + col;
        if (RESID) v += resid[idx];
        if (WF32) Cf[idx] = v; else Cb[idx] = f2bf(v);
      }
    }
  }
}

// ---- flash attention v5: LDS-staged K/V (dbuf, swizzled), swapped QK^T in-reg softmax ----
// grid (B*H, T/64); 4 waves x 16 Q rows; K/V tiles shared by all waves via LDS.
// LDS layout: tile = 64 rows x 8 chunks(16B); stored chunk = orig_chunk ^ (row&7)
// (pre-swizzled global source + same XOR on read: G21 both-sides rule).
template<int CAUSAL>
__global__ __launch_bounds__(256, 4)
void attn_k(const short* __restrict__ Q, int ldq,
            const short* __restrict__ K, int ldk,
            const short* __restrict__ Vt, int ldvt,   // Vt[b*H+h][d][s]
            const int* __restrict__ msk,
            short* __restrict__ O, int ldo,
            int H, int Tq, int Sk)
{
  __shared__ short kls[2][4096];
  __shared__ short vls[2][4096];
  const int bh = blockIdx.x;
  const int b = bh / H, h = bh % H;
  const int tid = threadIdx.x;
  const int wave = tid>>6, lane = tid&63;
  const int lo = lane&15, hi = lane>>4;
  const int t0 = blockIdx.y*64 + wave*16;

  const short* Qb  = Q + (size_t)(b*Tq)*ldq + h*64;
  const short* Kb  = K + (size_t)(b*Sk)*ldk + h*64;
  const short* Vtb = Vt + (size_t)bh*64*ldvt;
  const int*   mb  = msk + (size_t)b*Sk;

  // Q as MFMA B-operand: row j = lo -> q-row t0+lo, k = 8*hi+e
  const short* qp = Qb + (size_t)(t0+lo)*ldq + hi*8;
  const s8v qa0 = *(const s8v*)(qp);
  const s8v qa1 = *(const s8v*)(qp + 32);

  float mrow = -INFINITY, lrow = 0.f;
  f32x4 oacc[4] = {};
  const int trow = t0 + lo;
  const int nblk = CAUSAL ? (blockIdx.y + 1) : (Sk>>6);
  const float sc2 = 0.03125f * 1.44269504088896f;   // E^-0.5 * log2(e)
  const int x8 = lo & 7;

  // stage K tile (rows = s) and V tile (rows = d) for KV-block `it`
  auto stage = [&](int buf, int it){
    const int s0 = it*64;
    #pragma unroll
    for (int rd=0; rd<2; rd++){
      const int q = rd*256 + tid;          // linear 16B-chunk index 0..511
      const int r = q>>3, c = q&7;
      const int cs = (c ^ (r&7))*8;        // pre-swizzled source chunk (elements)
      __builtin_amdgcn_global_load_lds(
        (const __attribute__((address_space(1))) void*)(Kb + (size_t)(s0+r)*ldk + cs),
        (__attribute__((address_space(3))) void*)(&kls[buf][(rd*256 + wave*64)*8]),
        16, 0, 0);
      __builtin_amdgcn_global_load_lds(
        (const __attribute__((address_space(1))) void*)(Vtb + (size_t)r*ldvt + s0 + cs),
        (__attribute__((address_space(3))) void*)(&vls[buf][(rd*256 + wave*64)*8]),
        16, 0, 0);
    }
  };

  stage(0, 0);
  int cur = 0;
  for (int it=0; it<nblk; it++){
    __syncthreads();                       // staged tile visible (drains vmcnt)
    if (it+1 < nblk) stage(cur^1, it+1);   // prefetch overlaps compute below
    const int s0 = it*64;

    // ---- mask (int4 over s = s0+16g+4hi+{0..3}) ----
    int ka[4][4];
    #pragma unroll
    for (int g=0; g<4; g++){
      const int4 kv = ((const int4*)mb)[(s0>>2) + g*4 + hi];
      ka[g][0]=kv.x; ka[g][1]=kv.y; ka[g][2]=kv.z; ka[g][3]=kv.w;
    }

    // ---- K fragments from LDS (swapped A-operand): row = 16g+lo, chunks hi, 4+hi ----
    const short* kl = kls[cur];
    s8v kf[4][2];
    #pragma unroll
    for (int g=0; g<4; g++){
      const int rb = (g*16 + lo)*64;
      kf[g][0] = *(const s8v*)(kl + rb + ((hi     ^ x8)*8));
      kf[g][1] = *(const s8v*)(kl + rb + (((4+hi) ^ x8)*8));
    }

    // ---- QK^T swapped: S^T, lane holds S[t=lo][s = s0+16g+4hi+r] ----
    f32x4 sg[4] = {};
    __builtin_amdgcn_s_setprio(1);
    #pragma unroll
    for (int g=0; g<4; g++){
      sg[g] = mfma16(kf[g][0], qa0, sg[g]);
      sg[g] = mfma16(kf[g][1], qa1, sg[g]);
    }
    __builtin_amdgcn_s_setprio(0);

    // ---- scale + mask ----
    const bool lastblk = CAUSAL && (it == nblk-1);
    float p[4][4];
    #pragma unroll
    for (int g=0; g<4; g++)
      #pragma unroll
      for (int r=0; r<4; r++){
        const int sidx = s0 + g*16 + 4*hi + r;
        const bool ok = ka[g][r] && (!lastblk || sidx <= trow);
        p[g][r] = ok ? sg[g][r]*sc2 : -1.5e9f;
      }

    // ---- row max: in-lane tree + 2 cross-lane rounds ----
    float bmax;
    {
      float m0_ = fmaxf(fmaxf(p[0][0],p[0][1]), fmaxf(p[0][2],p[0][3]));
      float m1_ = fmaxf(fmaxf(p[1][0],p[1][1]), fmaxf(p[1][2],p[1][3]));
      float m2_ = fmaxf(fmaxf(p[2][0],p[2][1]), fmaxf(p[2][2],p[2][3]));
      float m3_ = fmaxf(fmaxf(p[3][0],p[3][1]), fmaxf(p[3][2],p[3][3]));
      bmax = fmaxf(fmaxf(m0_,m1_), fmaxf(m2_,m3_));
    }
    bmax = fmaxf(bmax, __shfl_xor(bmax, 16));
    bmax = fmaxf(bmax, __shfl_xor(bmax, 32));

    const float mn  = fmaxf(mrow, bmax);
    const float fac = exp2f(mrow - mn);        // first iter: exp2(-inf)=0
    mrow = mn;
    #pragma unroll
    for (int g=0; g<4; g++)
      #pragma unroll
      for (int r=0; r<4; r++)
        p[g][r] = exp2f(p[g][r] - mn);

    float bsum;
    {
      float s0_ = (p[0][0]+p[0][1]) + (p[0][2]+p[0][3]);
      float s1_ = (p[1][0]+p[1][1]) + (p[1][2]+p[1][3]);
      float s2_ = (p[2][0]+p[2][1]) + (p[2][2]+p[2][3]);
      float s3_ = (p[3][0]+p[3][1]) + (p[3][2]+p[3][3]);
      bsum = (s0_+s1_) + (s2_+s3_);
    }
    bsum += __shfl_xor(bsum, 16);
    bsum += __shfl_xor(bsum, 32);
    lrow = lrow*fac + bsum;
    #pragma unroll
    for (int f=0; f<4; f++)
      #pragma unroll
      for (int r=0; r<4; r++)
        oacc[f][r] *= fac;

    // ---- pack P -> bf16 B-operand (k-map: slot(hi,e) <-> s = ks*32+16*(e>>2)+4hi+(e&3)) ----
    u32x4 pw0, pw1;
    pw0[0] = cvtpk(p[0][0], p[0][1]);
    pw0[1] = cvtpk(p[0][2], p[0][3]);
    pw0[2] = cvtpk(p[1][0], p[1][1]);
    pw0[3] = cvtpk(p[1][2], p[1][3]);
    pw1[0] = cvtpk(p[2][0], p[2][1]);
    pw1[1] = cvtpk(p[2][2], p[2][3]);
    pw1[2] = cvtpk(p[3][0], p[3][1]);
    pw1[3] = cvtpk(p[3][2], p[3][3]);
    const s8v pb0 = __builtin_bit_cast(s8v, pw0);
    const s8v pb1 = __builtin_bit_cast(s8v, pw1);

    // ---- V fragments from LDS (same k-map) + PV: O^T accumulate ----
    const short* vl = vls[cur];
    __builtin_amdgcn_s_setprio(1);
    #pragma unroll
    for (int f=0; f<4; f++){
      const int rb = (f*16 + lo)*64;
      const int h2 = hi>>1, o2 = (hi&1)*4;
      const s4v a0 = *(const s4v*)(vl + rb + (((h2  ) ^ x8)*8) + o2);
      const s4v a1 = *(const s4v*)(vl + rb + (((2+h2) ^ x8)*8) + o2);
      const s4v a2 = *(const s4v*)(vl + rb + (((4+h2) ^ x8)*8) + o2);
      const s4v a3 = *(const s4v*)(vl + rb + (((6+h2) ^ x8)*8) + o2);
      const s8v av0 = __builtin_shufflevector(a0, a1, 0,1,2,3,4,5,6,7);
      const s8v av1 = __builtin_shufflevector(a2, a3, 0,1,2,3,4,5,6,7);
      oacc[f] = mfma16(av0, pb0, oacc[f]);
      oacc[f] = mfma16(av1, pb1, oacc[f]);
    }
    __builtin_amdgcn_s_setprio(0);
    cur ^= 1;
  }

  // ---- write O[t = t0+lo][d = f*16+4hi+r] : 8B stores ----
  const float inv = 1.0f / lrow;
  short* Ob = O + (size_t)(b*Tq)*ldo + h*64 + (size_t)(t0+lo)*ldo + 4*hi;
  #pragma unroll
  for (int f=0; f<4; f++){
    s4v o;
    #pragma unroll
    for (int r=0; r<4; r++) o[r] = f2bf(oacc[f][r]*inv);
    *(s4v*)(Ob + f*16) = o;
  }
}

// =============================== host ===============================
extern "C" void kernel_launch(void* const* d_in, const int* in_sizes, int n_in,
                              void* d_out, int out_size, void* d_ws, size_t ws_size,
                              hipStream_t stream)
{
  (void)in_sizes; (void)n_in; (void)out_size; (void)ws_size;
  const float* x    = (const float*)d_in[0];
  const int*   xm   = (const int*)  d_in[1];
  const float* ca   = (const float*)d_in[2];
  const int*   cam  = (const int*)  d_in[3];
  const float* Wq_s = (const float*)d_in[4];
  const float* Wk_s = (const float*)d_in[5];
  const float* Wv_s = (const float*)d_in[6];
  const float* Wo_s = (const float*)d_in[7];
  const float* bo_s = (const float*)d_in[8];
  const float* Wq_c = (const float*)d_in[9];
  const float* Wk_c = (const float*)d_in[10];
  const float* Wv_c = (const float*)d_in[11];
  const float* Wo_c = (const float*)d_in[12];
  const float* bo_c = (const float*)d_in[13];
  const float* ln1g = (const float*)d_in[14];
  const float* ln1b = (const float*)d_in[15];
  const float* ln2g = (const float*)d_in[16];
  const float* ln2b = (const float*)d_in[17];
  const float* ln3g = (const float*)d_in[18];
  const float* ln3b = (const float*)d_in[19];
  const float* W1   = (const float*)d_in[20];
  const float* b1   = (const float*)d_in[21];
  const float* W2   = (const float*)d_in[22];
  const float* b2   = (const float*)d_in[23];
  float* out = (float*)d_out;

  char* ws = (char*)d_ws;
  size_t off = 0;
  auto alloc = [&](size_t bytes)->void*{
    void* p = ws + off; off += (bytes + 255) & ~(size_t)255; return p; };

  short* w_qkv_s = (short*)alloc((size_t)3072*1024*2);
  short* w_o_s   = (short*)alloc((size_t)1024*1024*2);
  short* w_q_c   = (short*)alloc((size_t)1024*1024*2);
  short* w_kv_c  = (short*)alloc((size_t)2048*1024*2);
  short* w_o_c   = (short*)alloc((size_t)1024*1024*2);
  short* w_1     = (short*)alloc((size_t)4096*1024*2);
  short* w_2     = (short*)alloc((size_t)1024*4096*2);
  short* xn      = (short*)alloc((size_t)4096*1024*2);
  short* cab     = (short*)alloc((size_t)4096*1024*2);
  short* qkv     = (short*)alloc((size_t)4096*3072*2);
  short* attno   = (short*)alloc((size_t)4096*1024*2);
  float* xres    = (float*)alloc((size_t)4096*1024*4);
  short* hffn    = (short*)alloc((size_t)4096*4096*2);
  short* kvbuf   = qkv + (size_t)4096*1024;
  // Vt buffers alias hffn (disjoint live ranges: attn phases vs FFN phase)
  short* vt_s    = hffn;                           // 64 heads * 64 * 1024
  short* vt_c    = hffn + (size_t)4*1024*1024;

  // weight repacks -> B^T (N,K) bf16
  tcast_k<<<dim3(32,  2,16),256,0,stream>>>(Wq_s, w_qkv_s,           1024,   64);
  tcast_k<<<dim3(32,  2,16),256,0,stream>>>(Wk_s, w_qkv_s+1024*1024, 1024,   64);
  tcast_k<<<dim3(32,  2,16),256,0,stream>>>(Wv_s, w_qkv_s+2048*1024, 1024,   64);
  tcast_k<<<dim3(32, 32, 1),256,0,stream>>>(Wo_s, w_o_s,             1024, 1024);
  tcast_k<<<dim3(32,  2,16),256,0,stream>>>(Wq_c, w_q_c,             1024,   64);
  tcast_k<<<dim3(32,  2,16),256,0,stream>>>(Wk_c, w_kv_c,            1024,   64);
  tcast_k<<<dim3(32,  2,16),256,0,stream>>>(Wv_c, w_kv_c+1024*1024,  1024,   64);
  tcast_k<<<dim3(32, 32, 1),256,0,stream>>>(Wo_c, w_o_c,             1024, 1024);
  tcast_k<<<dim3(32,128, 1),256,0,stream>>>(W1,   w_1,               1024, 4096);
  tcast_k<<<dim3(128,32, 1),256,0,stream>>>(W2,   w_2,               4096, 1024);
  cast_k<<<4096,256,0,stream>>>(ca, cab);

  // --- self attention ---
  ln_k<<<4096,256,0,stream>>>(x, ln1g, ln1b, xn);
  gemm_bt<0,0,0,0><<<dim3(24,32),256,0,stream>>>(xn, w_qkv_s, nullptr, nullptr,
                                                 qkv, nullptr, 4096, 3072, 1024);
  vtrans_k<<<dim3(32,2,64),256,0,stream>>>(qkv+2048, 3072, vt_s, 1024, 16);
  attn_k<1><<<dim3(64,16),256,0,stream>>>(qkv, 3072, qkv+1024, 3072, vt_s, 1024,
                                          xm, attno, 1024, 16, 1024, 1024);
  gemm_bt<1,0,1,1><<<dim3(8,32),256,0,stream>>>(attno, w_o_s, bo_s, x,
                                                nullptr, xres, 4096, 1024, 1024);

  // --- cross attention (K,V from raw ca) ---
  ln_k<<<4096,256,0,stream>>>(xres, ln2g, ln2b, xn);
  gemm_bt<0,0,0,0><<<dim3(8,32),256,0,stream>>>(xn, w_q_c, nullptr, nullptr,
                                                qkv, nullptr, 4096, 1024, 1024);
  gemm_bt<0,0,0,0><<<dim3(16,32),256,0,stream>>>(cab, w_kv_c, nullptr, nullptr,
                                                 kvbuf, nullptr, 4096, 2048, 1024);
  vtrans_k<<<dim3(32,2,64),256,0,stream>>>(kvbuf+1024, 2048, vt_c, 1024, 16);
  attn_k<0><<<dim3(64,16),256,0,stream>>>(qkv, 1024, kvbuf, 2048, vt_c, 1024,
                                          cam, attno, 1024, 16, 1024, 1024);
  gemm_bt<1,0,1,1><<<dim3(8,32),256,0,stream>>>(attno, w_o_c, bo_c, xres,
                                                nullptr, xres, 4096, 1024, 1024);

  // --- FFN ---
  ln_k<<<4096,256,0,stream>>>(xres, ln3g, ln3b, xn);
  gemm_bt<1,1,0,0><<<dim3(32,32),256,0,stream>>>(xn, w_1, b1, nullptr,
                                                 hffn, nullptr, 4096, 4096, 1024);
  gemm_bt<1,0,1,1><<<dim3(8,32),256,0,stream>>>(hffn, w_2, b2, xres,
                                                nullptr, out, 4096, 1024, 4096);
}

// Round 6
// 381.314 us; speedup vs baseline: 1.5571x; 1.0289x over previous
//
#include <hip/hip_runtime.h>
#include <hip/hip_bf16.h>
#include <cstdint>
#include <cstddef>

typedef __attribute__((ext_vector_type(8))) short  s8v;
typedef __attribute__((ext_vector_type(4))) short  s4v;
typedef __attribute__((ext_vector_type(8))) __bf16 b8v;
typedef __attribute__((ext_vector_type(4))) float  f32x4;
typedef __attribute__((ext_vector_type(4))) unsigned u32x4;

__device__ __forceinline__ short f2bf(float f){
  unsigned u = __builtin_bit_cast(unsigned, f);
  unsigned r = (u + 0x7fffu + ((u >> 16) & 1u)) >> 16;   // RNE
  return (short)(unsigned short)r;
}

__device__ __forceinline__ f32x4 mfma16(s8v a, s8v b, f32x4 c){
  return __builtin_amdgcn_mfma_f32_16x16x32_bf16(
      __builtin_bit_cast(b8v, a), __builtin_bit_cast(b8v, b), c, 0, 0, 0);
}

__device__ __forceinline__ unsigned cvtpk(float a, float b){
  unsigned w;
  asm("v_cvt_pk_bf16_f32 %0, %1, %2" : "=v"(w) : "v"(a), "v"(b));
  return w;
}

// ---------------- LayerNorm over E=1024 -> bf16 ----------------
__global__ __launch_bounds__(256)
void ln_k(const float* __restrict__ x, const float* __restrict__ g,
          const float* __restrict__ b, short* __restrict__ out)
{
  const int row = blockIdx.x, tid = threadIdx.x;
  const float4 v = ((const float4*)(x + (size_t)row*1024))[tid];
  float s  = v.x+v.y+v.z+v.w;
  float s2 = v.x*v.x+v.y*v.y+v.z*v.z+v.w*v.w;
  #pragma unroll
  for (int off=32; off; off>>=1){ s += __shfl_down(s, off); s2 += __shfl_down(s2, off); }
  __shared__ float red[8];
  const int wave = tid>>6, lane = tid&63;
  if (lane==0){ red[wave]=s; red[4+wave]=s2; }
  __syncthreads();
  s  = red[0]+red[1]+red[2]+red[3];
  s2 = red[4]+red[5]+red[6]+red[7];
  const float mean = s*(1.f/1024.f);
  const float rstd = rsqrtf(s2*(1.f/1024.f) - mean*mean + 1e-5f);
  const float4 gv = ((const float4*)g)[tid];
  const float4 bv = ((const float4*)b)[tid];
  s4v o;
  o[0] = f2bf((v.x-mean)*rstd*gv.x + bv.x);
  o[1] = f2bf((v.y-mean)*rstd*gv.y + bv.y);
  o[2] = f2bf((v.z-mean)*rstd*gv.z + bv.z);
  o[3] = f2bf((v.w-mean)*rstd*gv.w + bv.w);
  *(s4v*)(out + (size_t)row*1024 + tid*4) = o;
}

// ---------------- f32 -> bf16 cast (4 elems/thread) ----------------
__global__ __launch_bounds__(256)
void cast_k(const float* __restrict__ in, short* __restrict__ out)
{
  const int i = blockIdx.x*256 + threadIdx.x;
  const float4 v = ((const float4*)in)[i];
  s4v o; o[0]=f2bf(v.x); o[1]=f2bf(v.y); o[2]=f2bf(v.z); o[3]=f2bf(v.w);
  ((s4v*)out)[i] = o;
}

// ------- transpose+cast: in (gridDim.z, E2, D2) f32 -> out (gridDim.z*D2, E2) bf16 -------
__global__ __launch_bounds__(256)
void tcast_k(const float* __restrict__ in, short* __restrict__ out, int E2, int D2)
{
  __shared__ float t[32][33];
  const int h  = blockIdx.z;
  const int e0 = blockIdx.x*32, d0 = blockIdx.y*32;
  const int tx = threadIdx.x & 31, ty = threadIdx.x >> 5;
  const float* ip = in + (size_t)h*E2*D2;
  #pragma unroll
  for (int r = ty; r < 32; r += 8)
    t[r][tx] = ip[(size_t)(e0+r)*D2 + d0 + tx];
  __syncthreads();
  short* op = out + (size_t)h*D2*E2;
  #pragma unroll
  for (int r = ty; r < 32; r += 8)
    op[(size_t)(d0+r)*E2 + e0 + tx] = f2bf(t[tx][r]);
}

// ------- bf16 transpose: V (b, s, h, d) strided -> Vt[b][h][d][s] -------
__global__ __launch_bounds__(256)
void vtrans_k(const short* __restrict__ V, int ldv, short* __restrict__ Vt, int S, int H)
{
  __shared__ short t[32][34];
  const int bh = blockIdx.z;
  const int b = bh / H, h = bh % H;
  const int s0 = blockIdx.x*32, d0 = blockIdx.y*32;
  const int tx = threadIdx.x & 31, ty = threadIdx.x >> 5;
  const short* ip = V + (size_t)b*S*ldv + h*64;
  #pragma unroll
  for (int r = ty; r < 32; r += 8)
    t[r][tx] = ip[(size_t)(s0+r)*ldv + d0 + tx];
  __syncthreads();
  short* op = Vt + ((size_t)bh*64 + d0)*S + s0;
  #pragma unroll
  for (int r = ty; r < 32; r += 8)
    op[(size_t)r*S + tx] = t[tx][r];
}

// ------- bf16 MFMA GEMM: C = A(M,K) * Bt(N,K)^T -------
// m97 structure + T3/T4: 3-buffer LDS ring, depth-2 prefetch, counted vmcnt,
// raw s_barrier (one per iter), T1 bijective XCD swizzle on linear block id.
template<int BIAS, int RELU, int RESID, int WF32>
__global__ __launch_bounds__(256, 2)
void gemm_bt(const short* __restrict__ A, const short* __restrict__ Bt,
             const float* __restrict__ bias, const float* __restrict__ resid,
             short* __restrict__ Cb, float* __restrict__ Cf,
             int M, int N, int K)
{
  __shared__ short lds[3][2][128*32];
  // ---- T1: XCD-aware remap (all grids have nwg % 8 == 0) ----
  const int nwg = gridDim.x * gridDim.y;
  int id = blockIdx.y * gridDim.x + blockIdx.x;
  id = (id & 7) * (nwg >> 3) + (id >> 3);
  const int bx = id % gridDim.x, by = id / gridDim.x;
  const int m0 = by*128, n0 = bx*128;

  const int tid  = threadIdx.x;
  const int wave = tid>>6, lane = tid&63;
  const int lo = lane&15, hi = lane>>4;
  const int wm = wave>>1, wn = wave&1;

  f32x4 acc[4][4] = {};
  const int NK = K >> 5;

  auto stage = [&](int buf, int kt){
    const short* Ag = A  + (size_t)m0*K + kt*32;
    const short* Bg = Bt + (size_t)n0*K + kt*32;
    #pragma unroll
    for (int c=0;c<2;c++){
      const int q = (wave*2+c)*64 + lane;
      const int r = q>>2, cc = q&3;
      __builtin_amdgcn_global_load_lds(
        (const __attribute__((address_space(1))) void*)(Ag + (size_t)r*K + cc*8),
        (__attribute__((address_space(3))) void*)(&lds[buf][0][(wave*2+c)*512]),
        16, 0, 0);
      __builtin_amdgcn_global_load_lds(
        (const __attribute__((address_space(1))) void*)(Bg + (size_t)r*K + cc*8),
        (__attribute__((address_space(3))) void*)(&lds[buf][1][(wave*2+c)*512]),
        16, 0, 0);
    }
  };

  // prologue: two tiles in flight (8 vm-ops/wave)
  stage(0, 0);
  if (NK > 1) stage(1, 1);

  for (int kt=0; kt<NK; kt++){
    // counted wait: oldest stage (kt) fully landed; stage(kt+1)'s 4 ops may remain
    if (kt+1 < NK) asm volatile("s_waitcnt vmcnt(4)" ::: "memory");
    else           asm volatile("s_waitcnt vmcnt(0)" ::: "memory");
    __builtin_amdgcn_s_barrier();          // all waves' stage(kt) complete
    __builtin_amdgcn_sched_barrier(0);
    if (kt+2 < NK) stage((kt+2)%3, kt+2);  // keep pipeline 2 deep

    const short* la = &lds[kt%3][0][0];
    const short* lb = &lds[kt%3][1][0];
    s8v af[4], bfr[4];
    #pragma unroll
    for (int i=0;i<4;i++)
      af[i] = *(const s8v*)(la + (wm*64 + i*16 + lo)*32 + hi*8);
    #pragma unroll
    for (int j=0;j<4;j++)
      bfr[j] = *(const s8v*)(lb + (wn*64 + j*16 + lo)*32 + hi*8);
    #pragma unroll
    for (int i=0;i<4;i++)
      #pragma unroll
      for (int j=0;j<4;j++)
        acc[i][j] = mfma16(af[i], bfr[j], acc[i][j]);
  }

  #pragma unroll
  for (int i=0;i<4;i++){
    const int row = m0 + wm*64 + i*16 + hi*4;
    #pragma unroll
    for (int j=0;j<4;j++){
      const int col = n0 + wn*64 + j*16 + lo;
      const float bv = BIAS ? bias[col] : 0.0f;
      #pragma unroll
      for (int r=0;r<4;r++){
        float v = acc[i][j][r] + bv;
        if (RELU) v = fmaxf(v, 0.0f);
        const size_t idx = (size_t)(row + r)*N + col;
        if (RESID) v += resid[idx];
        if (WF32) Cf[idx] = v; else Cb[idx] = f2bf(v);
      }
    }
  }
}

// ---- flash attention v5: LDS-staged K/V (dbuf, swizzled), swapped QK^T in-reg softmax ----
// grid (B*H, T/64); 4 waves x 16 Q rows; K/V tiles shared by all waves via LDS.
template<int CAUSAL>
__global__ __launch_bounds__(256, 4)
void attn_k(const short* __restrict__ Q, int ldq,
            const short* __restrict__ K, int ldk,
            const short* __restrict__ Vt, int ldvt,   // Vt[b*H+h][d][s]
            const int* __restrict__ msk,
            short* __restrict__ O, int ldo,
            int H, int Tq, int Sk)
{
  __shared__ short kls[2][4096];
  __shared__ short vls[2][4096];
  const int bh = blockIdx.x;
  const int b = bh / H, h = bh % H;
  const int tid = threadIdx.x;
  const int wave = tid>>6, lane = tid&63;
  const int lo = lane&15, hi = lane>>4;
  const int t0 = blockIdx.y*64 + wave*16;

  const short* Qb  = Q + (size_t)(b*Tq)*ldq + h*64;
  const short* Kb  = K + (size_t)(b*Sk)*ldk + h*64;
  const short* Vtb = Vt + (size_t)bh*64*ldvt;
  const int*   mb  = msk + (size_t)b*Sk;

  const short* qp = Qb + (size_t)(t0+lo)*ldq + hi*8;
  const s8v qa0 = *(const s8v*)(qp);
  const s8v qa1 = *(const s8v*)(qp + 32);

  float mrow = -INFINITY, lrow = 0.f;
  f32x4 oacc[4] = {};
  const int trow = t0 + lo;
  const int nblk = CAUSAL ? (blockIdx.y + 1) : (Sk>>6);
  const float sc2 = 0.03125f * 1.44269504088896f;   // E^-0.5 * log2(e)
  const int x8 = lo & 7;

  auto stage = [&](int buf, int it){
    const int s0 = it*64;
    #pragma unroll
    for (int rd=0; rd<2; rd++){
      const int q = rd*256 + tid;
      const int r = q>>3, c = q&7;
      const int cs = (c ^ (r&7))*8;
      __builtin_amdgcn_global_load_lds(
        (const __attribute__((address_space(1))) void*)(Kb + (size_t)(s0+r)*ldk + cs),
        (__attribute__((address_space(3))) void*)(&kls[buf][(rd*256 + wave*64)*8]),
        16, 0, 0);
      __builtin_amdgcn_global_load_lds(
        (const __attribute__((address_space(1))) void*)(Vtb + (size_t)r*ldvt + s0 + cs),
        (__attribute__((address_space(3))) void*)(&vls[buf][(rd*256 + wave*64)*8]),
        16, 0, 0);
    }
  };

  stage(0, 0);
  int cur = 0;
  for (int it=0; it<nblk; it++){
    __syncthreads();
    if (it+1 < nblk) stage(cur^1, it+1);
    const int s0 = it*64;

    int ka[4][4];
    #pragma unroll
    for (int g=0; g<4; g++){
      const int4 kv = ((const int4*)mb)[(s0>>2) + g*4 + hi];
      ka[g][0]=kv.x; ka[g][1]=kv.y; ka[g][2]=kv.z; ka[g][3]=kv.w;
    }

    const short* kl = kls[cur];
    s8v kf[4][2];
    #pragma unroll
    for (int g=0; g<4; g++){
      const int rb = (g*16 + lo)*64;
      kf[g][0] = *(const s8v*)(kl + rb + ((hi     ^ x8)*8));
      kf[g][1] = *(const s8v*)(kl + rb + (((4+hi) ^ x8)*8));
    }

    f32x4 sg[4] = {};
    __builtin_amdgcn_s_setprio(1);
    #pragma unroll
    for (int g=0; g<4; g++){
      sg[g] = mfma16(kf[g][0], qa0, sg[g]);
      sg[g] = mfma16(kf[g][1], qa1, sg[g]);
    }
    __builtin_amdgcn_s_setprio(0);

    const bool lastblk = CAUSAL && (it == nblk-1);
    float p[4][4];
    #pragma unroll
    for (int g=0; g<4; g++)
      #pragma unroll
      for (int r=0; r<4; r++){
        const int sidx = s0 + g*16 + 4*hi + r;
        const bool ok = ka[g][r] && (!lastblk || sidx <= trow);
        p[g][r] = ok ? sg[g][r]*sc2 : -1.5e9f;
      }

    float bmax;
    {
      float m0_ = fmaxf(fmaxf(p[0][0],p[0][1]), fmaxf(p[0][2],p[0][3]));
      float m1_ = fmaxf(fmaxf(p[1][0],p[1][1]), fmaxf(p[1][2],p[1][3]));
      float m2_ = fmaxf(fmaxf(p[2][0],p[2][1]), fmaxf(p[2][2],p[2][3]));
      float m3_ = fmaxf(fmaxf(p[3][0],p[3][1]), fmaxf(p[3][2],p[3][3]));
      bmax = fmaxf(fmaxf(m0_,m1_), fmaxf(m2_,m3_));
    }
    bmax = fmaxf(bmax, __shfl_xor(bmax, 16));
    bmax = fmaxf(bmax, __shfl_xor(bmax, 32));

    const float mn  = fmaxf(mrow, bmax);
    const float fac = exp2f(mrow - mn);
    mrow = mn;
    #pragma unroll
    for (int g=0; g<4; g++)
      #pragma unroll
      for (int r=0; r<4; r++)
        p[g][r] = exp2f(p[g][r] - mn);

    float bsum;
    {
      float s0_ = (p[0][0]+p[0][1]) + (p[0][2]+p[0][3]);
      float s1_ = (p[1][0]+p[1][1]) + (p[1][2]+p[1][3]);
      float s2_ = (p[2][0]+p[2][1]) + (p[2][2]+p[2][3]);
      float s3_ = (p[3][0]+p[3][1]) + (p[3][2]+p[3][3]);
      bsum = (s0_+s1_) + (s2_+s3_);
    }
    bsum += __shfl_xor(bsum, 16);
    bsum += __shfl_xor(bsum, 32);
    lrow = lrow*fac + bsum;
    #pragma unroll
    for (int f=0; f<4; f++)
      #pragma unroll
      for (int r=0; r<4; r++)
        oacc[f][r] *= fac;

    u32x4 pw0, pw1;
    pw0[0] = cvtpk(p[0][0], p[0][1]);
    pw0[1] = cvtpk(p[0][2], p[0][3]);
    pw0[2] = cvtpk(p[1][0], p[1][1]);
    pw0[3] = cvtpk(p[1][2], p[1][3]);
    pw1[0] = cvtpk(p[2][0], p[2][1]);
    pw1[1] = cvtpk(p[2][2], p[2][3]);
    pw1[2] = cvtpk(p[3][0], p[3][1]);
    pw1[3] = cvtpk(p[3][2], p[3][3]);
    const s8v pb0 = __builtin_bit_cast(s8v, pw0);
    const s8v pb1 = __builtin_bit_cast(s8v, pw1);

    const short* vl = vls[cur];
    __builtin_amdgcn_s_setprio(1);
    #pragma unroll
    for (int f=0; f<4; f++){
      const int rb = (f*16 + lo)*64;
      const int h2 = hi>>1, o2 = (hi&1)*4;
      const s4v a0 = *(const s4v*)(vl + rb + (((h2  ) ^ x8)*8) + o2);
      const s4v a1 = *(const s4v*)(vl + rb + (((2+h2) ^ x8)*8) + o2);
      const s4v a2 = *(const s4v*)(vl + rb + (((4+h2) ^ x8)*8) + o2);
      const s4v a3 = *(const s4v*)(vl + rb + (((6+h2) ^ x8)*8) + o2);
      const s8v av0 = __builtin_shufflevector(a0, a1, 0,1,2,3,4,5,6,7);
      const s8v av1 = __builtin_shufflevector(a2, a3, 0,1,2,3,4,5,6,7);
      oacc[f] = mfma16(av0, pb0, oacc[f]);
      oacc[f] = mfma16(av1, pb1, oacc[f]);
    }
    __builtin_amdgcn_s_setprio(0);
    cur ^= 1;
  }

  const float inv = 1.0f / lrow;
  short* Ob = O + (size_t)(b*Tq)*ldo + h*64 + (size_t)(t0+lo)*ldo + 4*hi;
  #pragma unroll
  for (int f=0; f<4; f++){
    s4v o;
    #pragma unroll
    for (int r=0; r<4; r++) o[r] = f2bf(oacc[f][r]*inv);
    *(s4v*)(Ob + f*16) = o;
  }
}

// =============================== host ===============================
extern "C" void kernel_launch(void* const* d_in, const int* in_sizes, int n_in,
                              void* d_out, int out_size, void* d_ws, size_t ws_size,
                              hipStream_t stream)
{
  (void)in_sizes; (void)n_in; (void)out_size; (void)ws_size;
  const float* x    = (const float*)d_in[0];
  const int*   xm   = (const int*)  d_in[1];
  const float* ca   = (const float*)d_in[2];
  const int*   cam  = (const int*)  d_in[3];
  const float* Wq_s = (const float*)d_in[4];
  const float* Wk_s = (const float*)d_in[5];
  const float* Wv_s = (const float*)d_in[6];
  const float* Wo_s = (const float*)d_in[7];
  const float* bo_s = (const float*)d_in[8];
  const float* Wq_c = (const float*)d_in[9];
  const float* Wk_c = (const float*)d_in[10];
  const float* Wv_c = (const float*)d_in[11];
  const float* Wo_c = (const float*)d_in[12];
  const float* bo_c = (const float*)d_in[13];
  const float* ln1g = (const float*)d_in[14];
  const float* ln1b = (const float*)d_in[15];
  const float* ln2g = (const float*)d_in[16];
  const float* ln2b = (const float*)d_in[17];
  const float* ln3g = (const float*)d_in[18];
  const float* ln3b = (const float*)d_in[19];
  const float* W1   = (const float*)d_in[20];
  const float* b1   = (const float*)d_in[21];
  const float* W2   = (const float*)d_in[22];
  const float* b2   = (const float*)d_in[23];
  float* out = (float*)d_out;

  char* ws = (char*)d_ws;
  size_t off = 0;
  auto alloc = [&](size_t bytes)->void*{
    void* p = ws + off; off += (bytes + 255) & ~(size_t)255; return p; };

  short* w_qkv_s = (short*)alloc((size_t)3072*1024*2);
  short* w_o_s   = (short*)alloc((size_t)1024*1024*2);
  short* w_q_c   = (short*)alloc((size_t)1024*1024*2);
  short* w_kv_c  = (short*)alloc((size_t)2048*1024*2);
  short* w_o_c   = (short*)alloc((size_t)1024*1024*2);
  short* w_1     = (short*)alloc((size_t)4096*1024*2);
  short* w_2     = (short*)alloc((size_t)1024*4096*2);
  short* xn      = (short*)alloc((size_t)4096*1024*2);
  short* cab     = (short*)alloc((size_t)4096*1024*2);
  short* qkv     = (short*)alloc((size_t)4096*3072*2);
  short* attno   = (short*)alloc((size_t)4096*1024*2);
  float* xres    = (float*)alloc((size_t)4096*1024*4);
  short* hffn    = (short*)alloc((size_t)4096*4096*2);
  short* kvbuf   = qkv + (size_t)4096*1024;
  short* vt_s    = hffn;
  short* vt_c    = hffn + (size_t)4*1024*1024;

  tcast_k<<<dim3(32,  2,16),256,0,stream>>>(Wq_s, w_qkv_s,           1024,   64);
  tcast_k<<<dim3(32,  2,16),256,0,stream>>>(Wk_s, w_qkv_s+1024*1024, 1024,   64);
  tcast_k<<<dim3(32,  2,16),256,0,stream>>>(Wv_s, w_qkv_s+2048*1024, 1024,   64);
  tcast_k<<<dim3(32, 32, 1),256,0,stream>>>(Wo_s, w_o_s,             1024, 1024);
  tcast_k<<<dim3(32,  2,16),256,0,stream>>>(Wq_c, w_q_c,             1024,   64);
  tcast_k<<<dim3(32,  2,16),256,0,stream>>>(Wk_c, w_kv_c,            1024,   64);
  tcast_k<<<dim3(32,  2,16),256,0,stream>>>(Wv_c, w_kv_c+1024*1024,  1024,   64);
  tcast_k<<<dim3(32, 32, 1),256,0,stream>>>(Wo_c, w_o_c,             1024, 1024);
  tcast_k<<<dim3(32,128, 1),256,0,stream>>>(W1,   w_1,               1024, 4096);
  tcast_k<<<dim3(128,32, 1),256,0,stream>>>(W2,   w_2,               4096, 1024);
  cast_k<<<4096,256,0,stream>>>(ca, cab);

  // --- self attention ---
  ln_k<<<4096,256,0,stream>>>(x, ln1g, ln1b, xn);
  gemm_bt<0,0,0,0><<<dim3(24,32),256,0,stream>>>(xn, w_qkv_s, nullptr, nullptr,
                                                 qkv, nullptr, 4096, 3072, 1024);
  vtrans_k<<<dim3(32,2,64),256,0,stream>>>(qkv+2048, 3072, vt_s, 1024, 16);
  attn_k<1><<<dim3(64,16),256,0,stream>>>(qkv, 3072, qkv+1024, 3072, vt_s, 1024,
                                          xm, attno, 1024, 16, 1024, 1024);
  gemm_bt<1,0,1,1><<<dim3(8,32),256,0,stream>>>(attno, w_o_s, bo_s, x,
                                                nullptr, xres, 4096, 1024, 1024);

  // --- cross attention (K,V from raw ca) ---
  ln_k<<<4096,256,0,stream>>>(xres, ln2g, ln2b, xn);
  gemm_bt<0,0,0,0><<<dim3(8,32),256,0,stream>>>(xn, w_q_c, nullptr, nullptr,
                                                qkv, nullptr, 4096, 1024, 1024);
  gemm_bt<0,0,0,0><<<dim3(16,32),256,0,stream>>>(cab, w_kv_c, nullptr, nullptr,
                                                 kvbuf, nullptr, 4096, 2048, 1024);
  vtrans_k<<<dim3(32,2,64),256,0,stream>>>(kvbuf+1024, 2048, vt_c, 1024, 16);
  attn_k<0><<<dim3(64,16),256,0,stream>>>(qkv, 1024, kvbuf, 2048, vt_c, 1024,
                                          cam, attno, 1024, 16, 1024, 1024);
  gemm_bt<1,0,1,1><<<dim3(8,32),256,0,stream>>>(attno, w_o_c, bo_c, xres,
                                                nullptr, xres, 4096, 1024, 1024);

  // --- FFN ---
  ln_k<<<4096,256,0,stream>>>(xres, ln3g, ln3b, xn);
  gemm_bt<1,1,0,0><<<dim3(32,32),256,0,stream>>>(xn, w_1, b1, nullptr,
                                                 hffn, nullptr, 4096, 4096, 1024);
  gemm_bt<1,0,1,1><<<dim3(8,32),256,0,stream>>>(hffn, w_2, b2, xres,
                                                nullptr, out, 4096, 1024, 4096);
}